// Round 3
// baseline (900.340 us; speedup 1.0000x reference)
//
#include <hip/hip_runtime.h>
#include <cstdint>

// ---------------------------------------------------------------------------
// Complex differential attention block, MI355X (gfx950).
// B=2,H=8,S=1024,D=384.  Rows = B*H*S = 16384.
// fp16 MFMA (16x16x32), fp32 accumulate.  All MFMA kernels double-buffered.
// ---------------------------------------------------------------------------

typedef _Float16 f16;
typedef __attribute__((ext_vector_type(8))) _Float16 f16x8;
typedef __attribute__((ext_vector_type(4))) float    f32x4;

#define NROW      16384L
#define HALF_OUT  6291456L               // NROW*384
#define SCALE_QK  0.05103103630798288f   // 384^-0.5
#define LAMBDA_INIT 0.35550906759096926f

__device__ __forceinline__ void gl2lds16(const void* g, void* l) {
  __builtin_amdgcn_global_load_lds(
      (const __attribute__((address_space(1))) void*)(uintptr_t)g,
      (__attribute__((address_space(3))) void*)(uint32_t)(uintptr_t)l,
      16, 0, 0);
}

struct PeTab { const float* p[6]; float sgn[6]; };

enum { MODE_PROJ = 0, MODE_VT = 1, MODE_OUT = 2 };

// C[M,N] = A[M,K] @ W[N,K]^T.  256 thr (4 waves), tile 128xBN, BK=32, dbuf.
// grid = (N/BN, M/128)
template <int MODE, int BN>
__launch_bounds__(256, 2)
__global__ void gemm_kernel(const f16* __restrict__ A, int lda,
                            const f16* __restrict__ W, int ldw,
                            const float* __restrict__ bias, PeTab pe,
                            void* __restrict__ outp, int ldo, int K)
{
  constexpr int NT = BN / 32;          // 16-col tiles per wave
  __shared__ f16 As[2][128 * 32];
  __shared__ f16 Bs[2][BN * 32];
  const int t    = threadIdx.x;
  const int lane = t & 63;
  const int wave = t >> 6;
  const long row0 = (long)blockIdx.y * 128;
  const long col0 = (long)blockIdx.x * BN;
  const f16* Ab = A + row0 * (long)lda;
  const f16* Wb = W + col0 * (long)ldw;

  const int wm = (wave >> 1) * 64;
  const int wn = (wave & 1) * (BN / 2);
  const int lm = lane & 15;
  const int lk = (lane >> 4) * 8;

  f32x4 acc[4][NT] = {};

  auto stage = [&](int kk, int buf) {
#pragma unroll
    for (int j = 0; j < 2; ++j) {
      int sg = j * 256 + t, r = sg >> 2, c = (sg & 3) << 3;
      gl2lds16(Ab + (long)r * lda + kk + c, &As[buf][sg * 8]);
    }
#pragma unroll
    for (int j = 0; j < BN / 64; ++j) {
      int sg = j * 256 + t, r = sg >> 2, c = (sg & 3) << 3;
      gl2lds16(Wb + (long)r * ldw + kk + c, &Bs[buf][sg * 8]);
    }
  };

  stage(0, 0);
  __syncthreads();
  int buf = 0;
  for (int kk = 0; kk < K; kk += 32, buf ^= 1) {
    if (kk + 32 < K) stage(kk + 32, buf ^ 1);   // async prefetch into other buf
    f16x8 bfr[NT];
#pragma unroll
    for (int nt = 0; nt < NT; ++nt)
      bfr[nt] = *(const f16x8*)&Bs[buf][(wn + nt * 16 + lm) * 32 + lk];
#pragma unroll
    for (int mt = 0; mt < 4; ++mt) {
      f16x8 afr = *(const f16x8*)&As[buf][(wm + mt * 16 + lm) * 32 + lk];
#pragma unroll
      for (int nt = 0; nt < NT; ++nt)
        acc[mt][nt] = __builtin_amdgcn_mfma_f32_16x16x32_f16(afr, bfr[nt], acc[mt][nt], 0, 0, 0);
    }
    __syncthreads();
  }

  const int lm4 = (lane >> 4) * 4;
  const int ln  = lane & 15;
#pragma unroll
  for (int mt = 0; mt < 4; ++mt) {
#pragma unroll
    for (int nt = 0; nt < NT; ++nt) {
      int col = (int)col0 + wn + nt * 16 + ln;
#pragma unroll
      for (int r = 0; r < 4; ++r) {
        long row = row0 + wm + mt * 16 + lm4 + r;
        float c = acc[mt][nt][r];
        if (MODE == MODE_PROJ) {
          c += bias[col];
          int s2 = col / 384;
          int d  = col - s2 * 384;
          const float* pp = pe.p[s2];
          if (pp) c += pe.sgn[s2] * pp[row * 384 + d];
          ((f16*)outp)[row * (long)ldo + col] = (f16)c;
        } else if (MODE == MODE_VT) {
          c += bias[col];
          long bh = row >> 10, sx = row & 1023;
          ((f16*)outp)[(bh * 768 + col) * 1024 + sx] = (f16)c;   // Vt[bh][n][s]
        } else {  // MODE_OUT
          c += bias[col];
          float* of = (float*)outp;
          if (col < 384) of[row * 384 + col] = c;
          else           of[HALF_OUT + row * 384 + (col - 384)] = c;
        }
      }
    }
  }
}

// Scores for one (w, bh): A = QG[bh] cols [w*768 .. +767] = [q_r|q_i],
// B = Kc[bh] = [k_r|k_i].  s_r = qr.kr + qi.ki ; s_i = qi.kr - qr.ki.
// Epilogue |s|*scale -> fp16 logits.  grid = (8, 8, 32), z = w*16 + bh.
__launch_bounds__(256, 2)
__global__ void score_kernel(const f16* __restrict__ QG, const f16* __restrict__ Kc,
                             f16* __restrict__ P)
{
  __shared__ f16 AsL[2][128 * 32], AsH[2][128 * 32];
  __shared__ f16 BsL[2][128 * 32], BsH[2][128 * 32];
  const int t = threadIdx.x, lane = t & 63, wave = t >> 6;
  const int z = blockIdx.z, w = z >> 4, bh = z & 15;
  const long row0 = (long)blockIdx.y * 128, col0 = (long)blockIdx.x * 128;
  const f16* A = QG + (long)bh * 1024 * 2304 + row0 * 2304 + w * 768;
  const f16* B = Kc + (long)bh * 1024 * 768 + col0 * 768;
  f16* Pz = P + (long)z * 1024 * 1024;

  const int wm = (wave >> 1) * 64, wn = (wave & 1) * 64;
  const int lm = lane & 15, lk = (lane >> 4) * 8;
  f32x4 accr[4][4] = {}, acci[4][4] = {};

  auto stage = [&](int kk, int buf) {
#pragma unroll
    for (int j = 0; j < 2; ++j) {
      int sg = j * 256 + t, r = sg >> 2, c = (sg & 3) << 3;
      gl2lds16(A + (long)r * 2304 + kk + c,       &AsL[buf][sg * 8]);
      gl2lds16(A + (long)r * 2304 + 384 + kk + c, &AsH[buf][sg * 8]);
      gl2lds16(B + (long)r * 768 + kk + c,        &BsL[buf][sg * 8]);
      gl2lds16(B + (long)r * 768 + 384 + kk + c,  &BsH[buf][sg * 8]);
    }
  };

  stage(0, 0);
  __syncthreads();
  int buf = 0;
  for (int kk = 0; kk < 384; kk += 32, buf ^= 1) {
    if (kk + 32 < 384) stage(kk + 32, buf ^ 1);
    f16x8 bl[4], bh2[4];
#pragma unroll
    for (int nt = 0; nt < 4; ++nt) {
      bl[nt]  = *(const f16x8*)&BsL[buf][(wn + nt * 16 + lm) * 32 + lk];
      bh2[nt] = *(const f16x8*)&BsH[buf][(wn + nt * 16 + lm) * 32 + lk];
    }
#pragma unroll
    for (int mt = 0; mt < 4; ++mt) {
      f16x8 al  = *(const f16x8*)&AsL[buf][(wm + mt * 16 + lm) * 32 + lk];
      f16x8 ah  = *(const f16x8*)&AsH[buf][(wm + mt * 16 + lm) * 32 + lk];
      f16x8 nal = -al;
#pragma unroll
      for (int nt = 0; nt < 4; ++nt) {
        accr[mt][nt] = __builtin_amdgcn_mfma_f32_16x16x32_f16(al,  bl[nt],  accr[mt][nt], 0, 0, 0);
        accr[mt][nt] = __builtin_amdgcn_mfma_f32_16x16x32_f16(ah,  bh2[nt], accr[mt][nt], 0, 0, 0);
        acci[mt][nt] = __builtin_amdgcn_mfma_f32_16x16x32_f16(ah,  bl[nt],  acci[mt][nt], 0, 0, 0);
        acci[mt][nt] = __builtin_amdgcn_mfma_f32_16x16x32_f16(nal, bh2[nt], acci[mt][nt], 0, 0, 0);
      }
    }
    __syncthreads();
  }
  const int lm4 = (lane >> 4) * 4, ln = lane & 15;
#pragma unroll
  for (int mt = 0; mt < 4; ++mt)
#pragma unroll
    for (int nt = 0; nt < 4; ++nt) {
      int col = (int)col0 + wn + nt * 16 + ln;
#pragma unroll
      for (int r = 0; r < 4; ++r) {
        long row = row0 + wm + mt * 16 + lm4 + r;
        float sr = accr[mt][nt][r], si = acci[mt][nt][r];
        float m = sqrtf(sr * sr + si * si + 1e-8f) * SCALE_QK;
        Pz[row * 1024 + col] = (f16)m;
      }
    }
}

// Dual PV: O1 = P1 @ Vt^T(layout [bh][n][s]), O2 = P2 @ Vt, shared B stage.
// tile 128x128, K=1024, dbuf.  grid = (6, 8, 16), z = bh.
__launch_bounds__(256, 2)
__global__ void pv_kernel(const f16* __restrict__ P, const f16* __restrict__ Vt,
                          f16* __restrict__ O1, f16* __restrict__ O2)
{
  __shared__ f16 As1[2][128 * 32], As2[2][128 * 32], Bs[2][128 * 32];
  const int t = threadIdx.x, lane = t & 63, wave = t >> 6;
  const int bh = blockIdx.z;
  const long row0 = (long)blockIdx.y * 128, col0 = (long)blockIdx.x * 128;
  const f16* A1 = P + ((long)bh << 20) + row0 * 1024;
  const f16* A2 = P + ((long)(16 + bh) << 20) + row0 * 1024;
  const f16* B  = Vt + (long)bh * 768 * 1024 + col0 * 1024;

  const int wm = (wave >> 1) * 64, wn = (wave & 1) * 64;
  const int lm = lane & 15, lk = (lane >> 4) * 8;
  f32x4 ac1[4][4] = {}, ac2[4][4] = {};

  auto stage = [&](int kk, int buf) {
#pragma unroll
    for (int j = 0; j < 2; ++j) {
      int sg = j * 256 + t, r = sg >> 2, c = (sg & 3) << 3;
      gl2lds16(A1 + (long)r * 1024 + kk + c, &As1[buf][sg * 8]);
      gl2lds16(A2 + (long)r * 1024 + kk + c, &As2[buf][sg * 8]);
      gl2lds16(B  + (long)r * 1024 + kk + c, &Bs[buf][sg * 8]);
    }
  };

  stage(0, 0);
  __syncthreads();
  int buf = 0;
  for (int kk = 0; kk < 1024; kk += 32, buf ^= 1) {
    if (kk + 32 < 1024) stage(kk + 32, buf ^ 1);
    f16x8 bfr[4];
#pragma unroll
    for (int nt = 0; nt < 4; ++nt)
      bfr[nt] = *(const f16x8*)&Bs[buf][(wn + nt * 16 + lm) * 32 + lk];
#pragma unroll
    for (int mt = 0; mt < 4; ++mt) {
      f16x8 a1 = *(const f16x8*)&As1[buf][(wm + mt * 16 + lm) * 32 + lk];
      f16x8 a2 = *(const f16x8*)&As2[buf][(wm + mt * 16 + lm) * 32 + lk];
#pragma unroll
      for (int nt = 0; nt < 4; ++nt) {
        ac1[mt][nt] = __builtin_amdgcn_mfma_f32_16x16x32_f16(a1, bfr[nt], ac1[mt][nt], 0, 0, 0);
        ac2[mt][nt] = __builtin_amdgcn_mfma_f32_16x16x32_f16(a2, bfr[nt], ac2[mt][nt], 0, 0, 0);
      }
    }
    __syncthreads();
  }
  const int lm4 = (lane >> 4) * 4, ln = lane & 15;
#pragma unroll
  for (int mt = 0; mt < 4; ++mt)
#pragma unroll
    for (int nt = 0; nt < 4; ++nt) {
      int col = (int)col0 + wn + nt * 16 + ln;
#pragma unroll
      for (int r = 0; r < 4; ++r) {
        long row = (long)bh * 1024 + row0 + wm + mt * 16 + lm4 + r;
        O1[row * 768 + col] = (f16)ac1[mt][nt][r];
        O2[row * 768 + col] = (f16)ac2[mt][nt][r];
      }
    }
}

// In-place row softmax over 1024 logits; 1 wave per row.
__global__ void softmax_kernel(f16* __restrict__ P)
{
  const long row = blockIdx.x;
  f16* p = P + row * 1024;
  const int lane = threadIdx.x;
  f16x8 v0 = *(const f16x8*)(p + lane * 16);
  f16x8 v1 = *(const f16x8*)(p + lane * 16 + 8);
  float x[16];
#pragma unroll
  for (int i = 0; i < 8; ++i) { x[i] = (float)v0[i]; x[8 + i] = (float)v1[i]; }
  float m = x[0];
#pragma unroll
  for (int i = 1; i < 16; ++i) m = fmaxf(m, x[i]);
#pragma unroll
  for (int off = 1; off < 64; off <<= 1) m = fmaxf(m, __shfl_xor(m, off));
  float s = 0.f;
#pragma unroll
  for (int i = 0; i < 16; ++i) { x[i] = __expf(x[i] - m); s += x[i]; }
#pragma unroll
  for (int off = 1; off < 64; off <<= 1) s += __shfl_xor(s, off);
  float inv = 1.f / s;
  f16x8 o0, o1;
#pragma unroll
  for (int i = 0; i < 8; ++i) { o0[i] = (f16)(x[i] * inv); o1[i] = (f16)(x[8 + i] * inv); }
  *(f16x8*)(p + lane * 16)     = o0;
  *(f16x8*)(p + lane * 16 + 8) = o1;
}

// RMSNorm over cat(a1,a2) + lambda diff + complex gate -> Xatt fp16.
// G lives in QG cols 1536..2303.
__global__ void fuse_kernel(const f16* __restrict__ A1, const f16* __restrict__ A2,
                            const f16* __restrict__ QG, const float* __restrict__ subw,
                            const float* __restrict__ lamp, f16* __restrict__ Xatt)
{
  const long row = blockIdx.x;
  const int t = threadIdx.x, lane = t & 63, wv = t >> 6;
  const f16* a1 = A1 + row * 768;
  const f16* a2 = A2 + row * 768;
  const f16* g  = QG + row * 2304 + 1536;
  float a1r[3], a1i[3], a2r[3], a2i[3];
  float ss = 0.f;
#pragma unroll
  for (int q = 0; q < 3; ++q) {
    int d = t + q * 128;
    a1r[q] = (float)a1[d]; a1i[q] = (float)a1[d + 384];
    a2r[q] = (float)a2[d]; a2i[q] = (float)a2[d + 384];
    ss += a1r[q] * a1r[q] + a1i[q] * a1i[q] + a2r[q] * a2r[q] + a2i[q] * a2i[q];
  }
#pragma unroll
  for (int m = 1; m < 64; m <<= 1) ss += __shfl_xor(ss, m);
  __shared__ float part[2];
  if (lane == 0) part[wv] = ss;
  __syncthreads();
  float inv = rsqrtf((part[0] + part[1]) * (1.f / 768.f) + 1e-5f);
  float lam = lamp[0];
#pragma unroll
  for (int q = 0; q < 3; ++q) {
    int d = t + q * 128;
    float w1 = subw[d], w2 = subw[d + 384];
    float n1r = a1r[q] * inv * w1, n1i = a1i[q] * inv * w1;
    float n2r = a2r[q] * inv * w2, n2i = a2i[q] * inv * w2;
    float orr = n1r - lam * n2r, oii = n1i - lam * n2i;
    float gr = (float)g[d], gi = (float)g[d + 384];
    Xatt[row * 768 + d]       = (f16)(gr * orr - gi * oii);
    Xatt[row * 768 + d + 384] = (f16)(gr * oii + gi * orr);
  }
}

__global__ void lam_kernel(const float* lq1, const float* lk1,
                           const float* lq2, const float* lk2, float* out)
{
  const int t = threadIdx.x, lane = t & 63, wv = t >> 6;
  float s1 = 0.f, s2 = 0.f;
#pragma unroll
  for (int q = 0; q < 3; ++q) {
    int d = t + q * 128;
    s1 += lq1[d] * lk1[d];
    s2 += lq2[d] * lk2[d];
  }
#pragma unroll
  for (int m = 1; m < 64; m <<= 1) { s1 += __shfl_xor(s1, m); s2 += __shfl_xor(s2, m); }
  __shared__ float p1[2], p2[2];
  if (lane == 0) { p1[wv] = s1; p2[wv] = s2; }
  __syncthreads();
  if (t == 0) {
    float x = expf(p1[0] + p1[1]) - expf(p2[0] + p2[1]) + LAMBDA_INIT;
    out[0] = 1.f / (1.f + expf(-x));
  }
}

// X = [xr | xi] fp16, row-major [16384][768]
__global__ void pack_x(const float* __restrict__ xr, const float* __restrict__ xi,
                       f16* __restrict__ X)
{
  long i = (long)blockIdx.x * 256 + threadIdx.x;
  long row = i / 768;
  int  c   = (int)(i - row * 768);
  float v = (c < 384) ? xr[row * 384 + c] : xi[row * 384 + (c - 384)];
  X[i] = (f16)v;
}

// Wq' [2304][768]: sections of 384 rows: 0:q1_r 1:q1_i 2:q2_r 3:q2_i 4:g_r 5:g_i
__global__ void pack_wq(const float* wq_r, const float* wq_i,
                        const float* wg_r, const float* wg_i,
                        const float* bq_r, const float* bq_i,
                        const float* bg_r, const float* bg_i,
                        f16* __restrict__ Wp, float* __restrict__ bp)
{
  long i = (long)blockIdx.x * 256 + threadIdx.x;   // < 2304*768
  int n = (int)(i / 768), e = (int)(i % 768);
  int s = n / 384, d = n - s * 384;
  int hb = (e >= 384);
  int ee = e - hb * 384;
  float v = 0.f, b = 0.f;
  switch (s) {
    case 0: v = hb ? -wq_i[d * 384 + ee]         :  wq_r[d * 384 + ee];         b = bq_r[d];       break;
    case 1: v = hb ?  wq_r[d * 384 + ee]         :  wq_i[d * 384 + ee];         b = bq_i[d];       break;
    case 2: v = hb ? -wq_i[(384 + d) * 384 + ee] :  wq_r[(384 + d) * 384 + ee]; b = bq_r[384 + d]; break;
    case 3: v = hb ?  wq_r[(384 + d) * 384 + ee] :  wq_i[(384 + d) * 384 + ee]; b = bq_i[384 + d]; break;
    case 4: v = hb ? -wg_i[d * 384 + ee]         :  wg_r[d * 384 + ee];         b = bg_r[d];       break;
    case 5: v = hb ?  wg_r[d * 384 + ee]         :  wg_i[d * 384 + ee];         b = bg_i[d];       break;
  }
  Wp[i] = (f16)v;
  if (e == 0) bp[n] = b;
}

// standard complex-linear pack: rows [o_r(384) | o_i(384)]
__global__ void pack_w_std(const float* wr, const float* wi,
                           const float* br, const float* bi,
                           f16* __restrict__ Wp, float* __restrict__ bp)
{
  long i = (long)blockIdx.x * 256 + threadIdx.x;   // < 768*768
  int n = (int)(i / 768), e = (int)(i % 768);
  int hb = (e >= 384);
  int ee = e - hb * 384;
  float v, b;
  if (n < 384) { v = hb ? -wi[n * 384 + ee] : wr[n * 384 + ee]; b = br[n]; }
  else { int d = n - 384; v = hb ? wr[d * 384 + ee] : wi[d * 384 + ee]; b = bi[d]; }
  Wp[i] = (f16)v;
  if (e == 0) bp[n] = b;
}

// ---------------------------------------------------------------------------
extern "C" void kernel_launch(void* const* d_in, const int* in_sizes, int n_in,
                              void* d_out, int out_size, void* d_ws, size_t ws_size,
                              hipStream_t stream)
{
  const float* q_r    = (const float*)d_in[0];
  const float* q_i    = (const float*)d_in[1];
  const float* k_r    = (const float*)d_in[2];
  const float* k_i    = (const float*)d_in[3];
  const float* v_r    = (const float*)d_in[4];
  const float* v_i    = (const float*)d_in[5];
  const float* pe_q_r = (const float*)d_in[6];
  const float* pe_q_i = (const float*)d_in[7];
  const float* pe_k_r = (const float*)d_in[8];
  const float* pe_k_i = (const float*)d_in[9];
  const float* wq_r = (const float*)d_in[10];
  const float* wq_i = (const float*)d_in[11];
  const float* bq_r = (const float*)d_in[12];
  const float* bq_i = (const float*)d_in[13];
  const float* wk_r = (const float*)d_in[14];
  const float* wk_i = (const float*)d_in[15];
  const float* bk_r = (const float*)d_in[16];
  const float* bk_i = (const float*)d_in[17];
  const float* wv_r = (const float*)d_in[18];
  const float* wv_i = (const float*)d_in[19];
  const float* bv_r = (const float*)d_in[20];
  const float* bv_i = (const float*)d_in[21];
  const float* wg_r = (const float*)d_in[22];
  const float* wg_i = (const float*)d_in[23];
  const float* bg_r = (const float*)d_in[24];
  const float* bg_i = (const float*)d_in[25];
  const float* wo_r = (const float*)d_in[26];
  const float* wo_i = (const float*)d_in[27];
  const float* bo_r = (const float*)d_in[28];
  const float* bo_i = (const float*)d_in[29];
  const float* lam_q1 = (const float*)d_in[30];
  const float* lam_k1 = (const float*)d_in[31];
  const float* lam_q2 = (const float*)d_in[32];
  const float* lam_k2 = (const float*)d_in[33];
  const float* subln_w = (const float*)d_in[34];

  char* base = (char*)d_ws;
  size_t off = 0;
  auto alloc = [&](size_t bytes) -> void* {
    void* p = base + off;
    off = (off + bytes + 255) & ~(size_t)255;
    return p;
  };
  f16*   Wq   = (f16*)alloc(2304L * 768 * 2);
  f16*   Wk   = (f16*)alloc(768L * 768 * 2);
  f16*   Wv   = (f16*)alloc(768L * 768 * 2);
  f16*   Wo   = (f16*)alloc(768L * 768 * 2);
  float* bq   = (float*)alloc(2304 * 4);
  float* bk   = (float*)alloc(768 * 4);
  float* bv   = (float*)alloc(768 * 4);
  float* bo   = (float*)alloc(768 * 4);
  float* lamp = (float*)alloc(4);
  f16*   X    = (f16*)alloc(NROW * 768 * 2);
  f16*   QG   = (f16*)alloc(NROW * 2304 * 2);   // [q1|q2|g] per row
  f16*   Kc   = (f16*)alloc(NROW * 768 * 2);
  f16*   Vt   = (f16*)alloc(16L * 768 * 1024 * 2);
  f16*   P    = (f16*)alloc(32L * 1024 * 1024 * 2);
  if (off > ws_size) return;
  // overlays onto dead regions:
  f16* A1   = Kc;   // dead after score
  f16* A2   = X;    // dead after V projection
  f16* Xatt = Vt;   // dead after pv

  // --- weight / scalar prep ---
  pack_wq<<<6912, 256, 0, stream>>>(wq_r, wq_i, wg_r, wg_i, bq_r, bq_i, bg_r, bg_i, Wq, bq);
  pack_w_std<<<2304, 256, 0, stream>>>(wk_r, wk_i, bk_r, bk_i, Wk, bk);
  pack_w_std<<<2304, 256, 0, stream>>>(wv_r, wv_i, bv_r, bv_i, Wv, bv);
  pack_w_std<<<2304, 256, 0, stream>>>(wo_r, wo_i, bo_r, bo_i, Wo, bo);
  lam_kernel<<<1, 128, 0, stream>>>(lam_q1, lam_k1, lam_q2, lam_k2, lamp);

  PeTab pe0{};

  // --- Q+G path (fused, N=2304) ---
  pack_x<<<49152, 256, 0, stream>>>(q_r, q_i, X);
  PeTab peQ{};
  peQ.p[0] = pe_q_r; peQ.sgn[0] = 1.f;
  peQ.p[1] = pe_q_i; peQ.sgn[1] = 1.f;
  peQ.p[2] = pe_q_r; peQ.sgn[2] = 1.f;
  peQ.p[3] = pe_q_i; peQ.sgn[3] = 1.f;
  gemm_kernel<MODE_PROJ, 256><<<dim3(9, 128), 256, 0, stream>>>(
      X, 768, Wq, 768, bq, peQ, QG, 2304, 768);

  // --- K path ---
  pack_x<<<49152, 256, 0, stream>>>(k_r, k_i, X);
  PeTab peK{};
  peK.p[0] = pe_k_r; peK.sgn[0] = 1.f;
  peK.p[1] = pe_k_i; peK.sgn[1] = 1.f;
  gemm_kernel<MODE_PROJ, 128><<<dim3(6, 128), 256, 0, stream>>>(
      X, 768, Wk, 768, bk, peK, Kc, 768, 768);

  // --- V path (transposed output Vt[bh][n][s]) ---
  pack_x<<<49152, 256, 0, stream>>>(v_r, v_i, X);
  gemm_kernel<MODE_VT, 128><<<dim3(6, 128), 256, 0, stream>>>(
      X, 768, Wv, 768, bv, pe0, Vt, 0, 768);

  // --- attention ---
  score_kernel<<<dim3(8, 8, 32), 256, 0, stream>>>(QG, Kc, P);
  softmax_kernel<<<32768, 64, 0, stream>>>(P);
  pv_kernel<<<dim3(6, 8, 16), 256, 0, stream>>>(P, Vt, A1, A2);

  // --- norm + diff + gate ---
  fuse_kernel<<<16384, 128, 0, stream>>>(A1, A2, QG, subln_w, lamp, Xatt);

  // --- output projection ---
  gemm_kernel<MODE_OUT, 128><<<dim3(6, 128), 256, 0, stream>>>(
      Xatt, 768, Wo, 768, bo, pe0, d_out, 0, 768);

  (void)in_sizes; (void)n_in; (void)out_size;
}

// Round 4
// 833.770 us; speedup vs baseline: 1.0798x; 1.0798x over previous
//
#include <hip/hip_runtime.h>
#include <cstdint>

// ---------------------------------------------------------------------------
// Complex differential attention block, MI355X (gfx950).
// B=2,H=8,S=1024,D=384.  Rows = B*H*S = 16384.
// fp16 MFMA (16x16x32), fp32 accumulate.
// Single-buffered staging, BK=64 (2x32 sub-slabs), XCD-aware block swizzle.
// ---------------------------------------------------------------------------

typedef _Float16 f16;
typedef __attribute__((ext_vector_type(8))) _Float16 f16x8;
typedef __attribute__((ext_vector_type(4))) _Float16 f16x4;
typedef __attribute__((ext_vector_type(4))) float    f32x4;

#define NROW      16384L
#define HALF_OUT  6291456L               // NROW*384
#define SCALE_QK  0.05103103630798288f   // 384^-0.5
#define LAMBDA_INIT 0.35550906759096926f

__device__ __forceinline__ void gl2lds16(const void* g, void* l) {
  __builtin_amdgcn_global_load_lds(
      (const __attribute__((address_space(1))) void*)(uintptr_t)g,
      (__attribute__((address_space(3))) void*)(uint32_t)(uintptr_t)l,
      16, 0, 0);
}

struct PeTab { const float* p[6]; float sgn[6]; };

enum { MODE_PROJ = 0, MODE_VT = 1, MODE_OUT = 2 };

// C[M,N] = A[M,K] @ W[N,K]^T.  256 thr (4 waves), tile 128x128, BK=64
// (two 32-wide sub-buffers -> 32 MFMA per barrier).  1D grid, XCD swizzle:
// bid -> xcd=bid&7, per=bid>>3, bx=per%gx, by=xcd*16+per/gx  (M=16384 fixed).
template <int MODE>
__launch_bounds__(256, 2)
__global__ void gemm_kernel(const f16* __restrict__ A, int lda,
                            const f16* __restrict__ W, int ldw,
                            const float* __restrict__ bias, PeTab pe,
                            void* __restrict__ outp, int ldo, int K, int gx)
{
  __shared__ f16 As[2][128 * 32];
  __shared__ f16 Bs[2][128 * 32];
  const int t    = threadIdx.x;
  const int lane = t & 63;
  const int wave = t >> 6;
  const int bid  = blockIdx.x;
  const int xcd  = bid & 7;
  const int per  = bid >> 3;
  const long row0 = (long)(xcd * 16 + per / gx) * 128;
  const long col0 = (long)(per % gx) * 128;
  const f16* Ab = A + row0 * (long)lda;
  const f16* Wb = W + col0 * (long)ldw;

  const int wm = (wave >> 1) * 64;
  const int wn = (wave & 1) * 64;
  const int lm = lane & 15;
  const int lk = (lane >> 4) * 8;

  f32x4 acc[4][4] = {};

  auto stage = [&](int kk, int sub) {
#pragma unroll
    for (int j = 0; j < 2; ++j) {
      int sg = j * 256 + t, r = sg >> 2, c = (sg & 3) << 3;
      gl2lds16(Ab + (long)r * lda + kk + c, &As[sub][sg * 8]);
      gl2lds16(Wb + (long)r * ldw + kk + c, &Bs[sub][sg * 8]);
    }
  };

  for (int kk = 0; kk < K; kk += 64) {
    stage(kk, 0);
    stage(kk + 32, 1);
    __syncthreads();
#pragma unroll
    for (int sub = 0; sub < 2; ++sub) {
      f16x8 bfr[4];
#pragma unroll
      for (int nt = 0; nt < 4; ++nt)
        bfr[nt] = *(const f16x8*)&Bs[sub][(wn + nt * 16 + lm) * 32 + lk];
#pragma unroll
      for (int mt = 0; mt < 4; ++mt) {
        f16x8 afr = *(const f16x8*)&As[sub][(wm + mt * 16 + lm) * 32 + lk];
#pragma unroll
        for (int nt = 0; nt < 4; ++nt)
          acc[mt][nt] = __builtin_amdgcn_mfma_f32_16x16x32_f16(afr, bfr[nt], acc[mt][nt], 0, 0, 0);
      }
    }
    __syncthreads();
  }

  const int lm4 = (lane >> 4) * 4;
  const int ln  = lane & 15;
#pragma unroll
  for (int mt = 0; mt < 4; ++mt) {
#pragma unroll
    for (int nt = 0; nt < 4; ++nt) {
      int col = (int)col0 + wn + nt * 16 + ln;
      if (MODE == MODE_VT) {
        long rowb = row0 + wm + mt * 16 + lm4;
        long bh = rowb >> 10, sx = rowb & 1023;
        f16x4 v;
#pragma unroll
        for (int r = 0; r < 4; ++r) v[r] = (f16)(acc[mt][nt][r] + bias[col]);
        *(f16x4*)&((f16*)outp)[(bh * 768 + col) * 1024 + sx] = v;   // Vt[bh][n][s]
      } else {
#pragma unroll
        for (int r = 0; r < 4; ++r) {
          long row = row0 + wm + mt * 16 + lm4 + r;
          float c = acc[mt][nt][r] + bias[col];
          if (MODE == MODE_PROJ) {
            int s2 = col / 384;
            int d  = col - s2 * 384;
            const float* pp = pe.p[s2];
            if (pp) c += pe.sgn[s2] * pp[row * 384 + d];
            ((f16*)outp)[row * (long)ldo + col] = (f16)c;
          } else {  // MODE_OUT
            float* of = (float*)outp;
            if (col < 384) of[row * 384 + col] = c;
            else           of[HALF_OUT + row * 384 + (col - 384)] = c;
          }
        }
      }
    }
  }
}

// Scores for one (w, bh): A = QG[bh] cols [w*768 .. +767] = [q_r|q_i],
// B = Kc[bh] = [k_r|k_i].  s_r = qr.kr + qi.ki ; s_i = qi.kr - qr.ki.
// 64 MFMA per barrier from 4x8KB stage buffers.  |s|*scale -> fp16 logits.
// 1D grid 2048: xcd=bid&7, per=bid>>3, z=xcd*4+per/64, y=(per%64)/8, x=per%8.
__launch_bounds__(256, 2)
__global__ void score_kernel(const f16* __restrict__ QG, const f16* __restrict__ Kc,
                             f16* __restrict__ P)
{
  __shared__ f16 AsL[128 * 32], AsH[128 * 32], BsL[128 * 32], BsH[128 * 32];
  const int t = threadIdx.x, lane = t & 63, wave = t >> 6;
  const int bid = blockIdx.x;
  const int xcd = bid & 7, per = bid >> 3;
  const int z   = xcd * 4 + per / 64;
  const int rem = per % 64;
  const int w = z >> 4, bh = z & 15;
  const long row0 = (long)(rem / 8) * 128, col0 = (long)(rem % 8) * 128;
  const f16* A = QG + (long)bh * 1024 * 2304 + row0 * 2304 + w * 768;
  const f16* B = Kc + (long)bh * 1024 * 768 + col0 * 768;
  f16* Pz = P + (long)z * 1024 * 1024;

  const int wm = (wave >> 1) * 64, wn = (wave & 1) * 64;
  const int lm = lane & 15, lk = (lane >> 4) * 8;
  f32x4 accr[4][4] = {}, acci[4][4] = {};

  for (int kk = 0; kk < 384; kk += 32) {
#pragma unroll
    for (int j = 0; j < 2; ++j) {
      int sg = j * 256 + t, r = sg >> 2, c = (sg & 3) << 3;
      gl2lds16(A + (long)r * 2304 + kk + c,       &AsL[sg * 8]);
      gl2lds16(A + (long)r * 2304 + 384 + kk + c, &AsH[sg * 8]);
      gl2lds16(B + (long)r * 768 + kk + c,        &BsL[sg * 8]);
      gl2lds16(B + (long)r * 768 + 384 + kk + c,  &BsH[sg * 8]);
    }
    __syncthreads();
    f16x8 bl[4], bh2[4];
#pragma unroll
    for (int nt = 0; nt < 4; ++nt) {
      bl[nt]  = *(const f16x8*)&BsL[(wn + nt * 16 + lm) * 32 + lk];
      bh2[nt] = *(const f16x8*)&BsH[(wn + nt * 16 + lm) * 32 + lk];
    }
#pragma unroll
    for (int mt = 0; mt < 4; ++mt) {
      f16x8 al  = *(const f16x8*)&AsL[(wm + mt * 16 + lm) * 32 + lk];
      f16x8 ah  = *(const f16x8*)&AsH[(wm + mt * 16 + lm) * 32 + lk];
      f16x8 nal = -al;
#pragma unroll
      for (int nt = 0; nt < 4; ++nt) {
        accr[mt][nt] = __builtin_amdgcn_mfma_f32_16x16x32_f16(al,  bl[nt],  accr[mt][nt], 0, 0, 0);
        accr[mt][nt] = __builtin_amdgcn_mfma_f32_16x16x32_f16(ah,  bh2[nt], accr[mt][nt], 0, 0, 0);
        acci[mt][nt] = __builtin_amdgcn_mfma_f32_16x16x32_f16(ah,  bl[nt],  acci[mt][nt], 0, 0, 0);
        acci[mt][nt] = __builtin_amdgcn_mfma_f32_16x16x32_f16(nal, bh2[nt], acci[mt][nt], 0, 0, 0);
      }
    }
    __syncthreads();
  }
  const int lm4 = (lane >> 4) * 4, ln = lane & 15;
#pragma unroll
  for (int mt = 0; mt < 4; ++mt)
#pragma unroll
    for (int nt = 0; nt < 4; ++nt) {
      int col = (int)col0 + wn + nt * 16 + ln;
#pragma unroll
      for (int r = 0; r < 4; ++r) {
        long row = row0 + wm + mt * 16 + lm4 + r;
        float sr = accr[mt][nt][r], si = acci[mt][nt][r];
        float m = sqrtf(sr * sr + si * si + 1e-8f) * SCALE_QK;
        Pz[row * 1024 + col] = (f16)m;
      }
    }
}

// Dual PV: O1 = P1 @ Vt, O2 = P2 @ Vt (Vt layout [bh][n][s]), shared B stage.
// BK=64 via 6x8KB sub-buffers -> 64 MFMA per barrier.  K=1024, 16 iters.
// 1D grid 768: xcd=bid&7, per=bid>>3, bh=xcd*2+per/48, y=(per%48)/6, x=per%6.
__launch_bounds__(256, 2)
__global__ void pv_kernel(const f16* __restrict__ P, const f16* __restrict__ Vt,
                          f16* __restrict__ O1, f16* __restrict__ O2)
{
  __shared__ f16 As1[2][128 * 32], As2[2][128 * 32], Bs[2][128 * 32];
  const int t = threadIdx.x, lane = t & 63, wave = t >> 6;
  const int bid = blockIdx.x;
  const int xcd = bid & 7, per = bid >> 3;
  const int bh  = xcd * 2 + per / 48;
  const int rem = per % 48;
  const long row0 = (long)(rem / 6) * 128, col0 = (long)(rem % 6) * 128;
  const f16* A1 = P + ((long)bh << 20) + row0 * 1024;
  const f16* A2 = P + ((long)(16 + bh) << 20) + row0 * 1024;
  const f16* B  = Vt + (long)bh * 768 * 1024 + col0 * 1024;

  const int wm = (wave >> 1) * 64, wn = (wave & 1) * 64;
  const int lm = lane & 15, lk = (lane >> 4) * 8;
  f32x4 ac1[4][4] = {}, ac2[4][4] = {};

  auto stage = [&](int kk, int sub) {
#pragma unroll
    for (int j = 0; j < 2; ++j) {
      int sg = j * 256 + t, r = sg >> 2, c = (sg & 3) << 3;
      gl2lds16(A1 + (long)r * 1024 + kk + c, &As1[sub][sg * 8]);
      gl2lds16(A2 + (long)r * 1024 + kk + c, &As2[sub][sg * 8]);
      gl2lds16(B  + (long)r * 1024 + kk + c, &Bs[sub][sg * 8]);
    }
  };

  for (int kk = 0; kk < 1024; kk += 64) {
    stage(kk, 0);
    stage(kk + 32, 1);
    __syncthreads();
#pragma unroll
    for (int sub = 0; sub < 2; ++sub) {
      f16x8 bfr[4];
#pragma unroll
      for (int nt = 0; nt < 4; ++nt)
        bfr[nt] = *(const f16x8*)&Bs[sub][(wn + nt * 16 + lm) * 32 + lk];
#pragma unroll
      for (int mt = 0; mt < 4; ++mt) {
        f16x8 a1 = *(const f16x8*)&As1[sub][(wm + mt * 16 + lm) * 32 + lk];
        f16x8 a2 = *(const f16x8*)&As2[sub][(wm + mt * 16 + lm) * 32 + lk];
#pragma unroll
        for (int nt = 0; nt < 4; ++nt) {
          ac1[mt][nt] = __builtin_amdgcn_mfma_f32_16x16x32_f16(a1, bfr[nt], ac1[mt][nt], 0, 0, 0);
          ac2[mt][nt] = __builtin_amdgcn_mfma_f32_16x16x32_f16(a2, bfr[nt], ac2[mt][nt], 0, 0, 0);
        }
      }
    }
    __syncthreads();
  }
  const int lm4 = (lane >> 4) * 4, ln = lane & 15;
#pragma unroll
  for (int mt = 0; mt < 4; ++mt)
#pragma unroll
    for (int nt = 0; nt < 4; ++nt) {
      int col = (int)col0 + wn + nt * 16 + ln;
#pragma unroll
      for (int r = 0; r < 4; ++r) {
        long row = (long)bh * 1024 + row0 + wm + mt * 16 + lm4 + r;
        O1[row * 768 + col] = (f16)ac1[mt][nt][r];
        O2[row * 768 + col] = (f16)ac2[mt][nt][r];
      }
    }
}

// In-place row softmax over 1024 logits; 1 wave per row.
__global__ void softmax_kernel(f16* __restrict__ P)
{
  const long row = blockIdx.x;
  f16* p = P + row * 1024;
  const int lane = threadIdx.x;
  f16x8 v0 = *(const f16x8*)(p + lane * 16);
  f16x8 v1 = *(const f16x8*)(p + lane * 16 + 8);
  float x[16];
#pragma unroll
  for (int i = 0; i < 8; ++i) { x[i] = (float)v0[i]; x[8 + i] = (float)v1[i]; }
  float m = x[0];
#pragma unroll
  for (int i = 1; i < 16; ++i) m = fmaxf(m, x[i]);
#pragma unroll
  for (int off = 1; off < 64; off <<= 1) m = fmaxf(m, __shfl_xor(m, off));
  float s = 0.f;
#pragma unroll
  for (int i = 0; i < 16; ++i) { x[i] = __expf(x[i] - m); s += x[i]; }
#pragma unroll
  for (int off = 1; off < 64; off <<= 1) s += __shfl_xor(s, off);
  float inv = 1.f / s;
  f16x8 o0, o1;
#pragma unroll
  for (int i = 0; i < 8; ++i) { o0[i] = (f16)(x[i] * inv); o1[i] = (f16)(x[8 + i] * inv); }
  *(f16x8*)(p + lane * 16)     = o0;
  *(f16x8*)(p + lane * 16 + 8) = o1;
}

// RMSNorm over cat(a1,a2) + lambda diff + complex gate -> Xatt fp16.
// G lives in QG cols 1536..2303.
__global__ void fuse_kernel(const f16* __restrict__ A1, const f16* __restrict__ A2,
                            const f16* __restrict__ QG, const float* __restrict__ subw,
                            const float* __restrict__ lamp, f16* __restrict__ Xatt)
{
  const long row = blockIdx.x;
  const int t = threadIdx.x, lane = t & 63, wv = t >> 6;
  const f16* a1 = A1 + row * 768;
  const f16* a2 = A2 + row * 768;
  const f16* g  = QG + row * 2304 + 1536;
  float a1r[3], a1i[3], a2r[3], a2i[3];
  float ss = 0.f;
#pragma unroll
  for (int q = 0; q < 3; ++q) {
    int d = t + q * 128;
    a1r[q] = (float)a1[d]; a1i[q] = (float)a1[d + 384];
    a2r[q] = (float)a2[d]; a2i[q] = (float)a2[d + 384];
    ss += a1r[q] * a1r[q] + a1i[q] * a1i[q] + a2r[q] * a2r[q] + a2i[q] * a2i[q];
  }
#pragma unroll
  for (int m = 1; m < 64; m <<= 1) ss += __shfl_xor(ss, m);
  __shared__ float part[2];
  if (lane == 0) part[wv] = ss;
  __syncthreads();
  float inv = rsqrtf((part[0] + part[1]) * (1.f / 768.f) + 1e-5f);
  float lam = lamp[0];
#pragma unroll
  for (int q = 0; q < 3; ++q) {
    int d = t + q * 128;
    float w1 = subw[d], w2 = subw[d + 384];
    float n1r = a1r[q] * inv * w1, n1i = a1i[q] * inv * w1;
    float n2r = a2r[q] * inv * w2, n2i = a2i[q] * inv * w2;
    float orr = n1r - lam * n2r, oii = n1i - lam * n2i;
    float gr = (float)g[d], gi = (float)g[d + 384];
    Xatt[row * 768 + d]       = (f16)(gr * orr - gi * oii);
    Xatt[row * 768 + d + 384] = (f16)(gr * oii + gi * orr);
  }
}

__global__ void lam_kernel(const float* lq1, const float* lk1,
                           const float* lq2, const float* lk2, float* out)
{
  const int t = threadIdx.x, lane = t & 63, wv = t >> 6;
  float s1 = 0.f, s2 = 0.f;
#pragma unroll
  for (int q = 0; q < 3; ++q) {
    int d = t + q * 128;
    s1 += lq1[d] * lk1[d];
    s2 += lq2[d] * lk2[d];
  }
#pragma unroll
  for (int m = 1; m < 64; m <<= 1) { s1 += __shfl_xor(s1, m); s2 += __shfl_xor(s2, m); }
  __shared__ float p1[2], p2[2];
  if (lane == 0) { p1[wv] = s1; p2[wv] = s2; }
  __syncthreads();
  if (t == 0) {
    float x = expf(p1[0] + p1[1]) - expf(p2[0] + p2[1]) + LAMBDA_INIT;
    out[0] = 1.f / (1.f + expf(-x));
  }
}

// X = [xr | xi] fp16, row-major [16384][768]
__global__ void pack_x(const float* __restrict__ xr, const float* __restrict__ xi,
                       f16* __restrict__ X)
{
  long i = (long)blockIdx.x * 256 + threadIdx.x;
  long row = i / 768;
  int  c   = (int)(i - row * 768);
  float v = (c < 384) ? xr[row * 384 + c] : xi[row * 384 + (c - 384)];
  X[i] = (f16)v;
}

// Wq' [2304][768]: sections of 384 rows: 0:q1_r 1:q1_i 2:q2_r 3:q2_i 4:g_r 5:g_i
__global__ void pack_wq(const float* wq_r, const float* wq_i,
                        const float* wg_r, const float* wg_i,
                        const float* bq_r, const float* bq_i,
                        const float* bg_r, const float* bg_i,
                        f16* __restrict__ Wp, float* __restrict__ bp)
{
  long i = (long)blockIdx.x * 256 + threadIdx.x;   // < 2304*768
  int n = (int)(i / 768), e = (int)(i % 768);
  int s = n / 384, d = n - s * 384;
  int hb = (e >= 384);
  int ee = e - hb * 384;
  float v = 0.f, b = 0.f;
  switch (s) {
    case 0: v = hb ? -wq_i[d * 384 + ee]         :  wq_r[d * 384 + ee];         b = bq_r[d];       break;
    case 1: v = hb ?  wq_r[d * 384 + ee]         :  wq_i[d * 384 + ee];         b = bq_i[d];       break;
    case 2: v = hb ? -wq_i[(384 + d) * 384 + ee] :  wq_r[(384 + d) * 384 + ee]; b = bq_r[384 + d]; break;
    case 3: v = hb ?  wq_r[(384 + d) * 384 + ee] :  wq_i[(384 + d) * 384 + ee]; b = bq_i[384 + d]; break;
    case 4: v = hb ? -wg_i[d * 384 + ee]         :  wg_r[d * 384 + ee];         b = bg_r[d];       break;
    case 5: v = hb ?  wg_r[d * 384 + ee]         :  wg_i[d * 384 + ee];         b = bg_i[d];       break;
  }
  Wp[i] = (f16)v;
  if (e == 0) bp[n] = b;
}

// standard complex-linear pack: rows [o_r(384) | o_i(384)]
__global__ void pack_w_std(const float* wr, const float* wi,
                           const float* br, const float* bi,
                           f16* __restrict__ Wp, float* __restrict__ bp)
{
  long i = (long)blockIdx.x * 256 + threadIdx.x;   // < 768*768
  int n = (int)(i / 768), e = (int)(i % 768);
  int hb = (e >= 384);
  int ee = e - hb * 384;
  float v, b;
  if (n < 384) { v = hb ? -wi[n * 384 + ee] : wr[n * 384 + ee]; b = br[n]; }
  else { int d = n - 384; v = hb ? wr[d * 384 + ee] : wi[d * 384 + ee]; b = bi[d]; }
  Wp[i] = (f16)v;
  if (e == 0) bp[n] = b;
}

// ---------------------------------------------------------------------------
extern "C" void kernel_launch(void* const* d_in, const int* in_sizes, int n_in,
                              void* d_out, int out_size, void* d_ws, size_t ws_size,
                              hipStream_t stream)
{
  const float* q_r    = (const float*)d_in[0];
  const float* q_i    = (const float*)d_in[1];
  const float* k_r    = (const float*)d_in[2];
  const float* k_i    = (const float*)d_in[3];
  const float* v_r    = (const float*)d_in[4];
  const float* v_i    = (const float*)d_in[5];
  const float* pe_q_r = (const float*)d_in[6];
  const float* pe_q_i = (const float*)d_in[7];
  const float* pe_k_r = (const float*)d_in[8];
  const float* pe_k_i = (const float*)d_in[9];
  const float* wq_r = (const float*)d_in[10];
  const float* wq_i = (const float*)d_in[11];
  const float* bq_r = (const float*)d_in[12];
  const float* bq_i = (const float*)d_in[13];
  const float* wk_r = (const float*)d_in[14];
  const float* wk_i = (const float*)d_in[15];
  const float* bk_r = (const float*)d_in[16];
  const float* bk_i = (const float*)d_in[17];
  const float* wv_r = (const float*)d_in[18];
  const float* wv_i = (const float*)d_in[19];
  const float* bv_r = (const float*)d_in[20];
  const float* bv_i = (const float*)d_in[21];
  const float* wg_r = (const float*)d_in[22];
  const float* wg_i = (const float*)d_in[23];
  const float* bg_r = (const float*)d_in[24];
  const float* bg_i = (const float*)d_in[25];
  const float* wo_r = (const float*)d_in[26];
  const float* wo_i = (const float*)d_in[27];
  const float* bo_r = (const float*)d_in[28];
  const float* bo_i = (const float*)d_in[29];
  const float* lam_q1 = (const float*)d_in[30];
  const float* lam_k1 = (const float*)d_in[31];
  const float* lam_q2 = (const float*)d_in[32];
  const float* lam_k2 = (const float*)d_in[33];
  const float* subln_w = (const float*)d_in[34];

  char* base = (char*)d_ws;
  size_t off = 0;
  auto alloc = [&](size_t bytes) -> void* {
    void* p = base + off;
    off = (off + bytes + 255) & ~(size_t)255;
    return p;
  };
  f16*   Wq   = (f16*)alloc(2304L * 768 * 2);
  f16*   Wk   = (f16*)alloc(768L * 768 * 2);
  f16*   Wv   = (f16*)alloc(768L * 768 * 2);
  f16*   Wo   = (f16*)alloc(768L * 768 * 2);
  float* bq   = (float*)alloc(2304 * 4);
  float* bk   = (float*)alloc(768 * 4);
  float* bv   = (float*)alloc(768 * 4);
  float* bo   = (float*)alloc(768 * 4);
  float* lamp = (float*)alloc(4);
  f16*   X    = (f16*)alloc(NROW * 768 * 2);
  f16*   QG   = (f16*)alloc(NROW * 2304 * 2);   // [q1|q2|g] per row
  f16*   Kc   = (f16*)alloc(NROW * 768 * 2);
  f16*   Vt   = (f16*)alloc(16L * 768 * 1024 * 2);
  f16*   P    = (f16*)alloc(32L * 1024 * 1024 * 2);
  if (off > ws_size) return;
  // overlays onto dead regions:
  f16* A1   = Kc;   // dead after score
  f16* A2   = X;    // dead after V projection
  f16* Xatt = Vt;   // dead after pv

  // --- weight / scalar prep ---
  pack_wq<<<6912, 256, 0, stream>>>(wq_r, wq_i, wg_r, wg_i, bq_r, bq_i, bg_r, bg_i, Wq, bq);
  pack_w_std<<<2304, 256, 0, stream>>>(wk_r, wk_i, bk_r, bk_i, Wk, bk);
  pack_w_std<<<2304, 256, 0, stream>>>(wv_r, wv_i, bv_r, bv_i, Wv, bv);
  pack_w_std<<<2304, 256, 0, stream>>>(wo_r, wo_i, bo_r, bo_i, Wo, bo);
  lam_kernel<<<1, 128, 0, stream>>>(lam_q1, lam_k1, lam_q2, lam_k2, lamp);

  PeTab pe0{};

  // --- Q+G path (fused, N=2304 -> gx=18, 2304 blocks) ---
  pack_x<<<49152, 256, 0, stream>>>(q_r, q_i, X);
  PeTab peQ{};
  peQ.p[0] = pe_q_r; peQ.sgn[0] = 1.f;
  peQ.p[1] = pe_q_i; peQ.sgn[1] = 1.f;
  peQ.p[2] = pe_q_r; peQ.sgn[2] = 1.f;
  peQ.p[3] = pe_q_i; peQ.sgn[3] = 1.f;
  gemm_kernel<MODE_PROJ><<<2304, 256, 0, stream>>>(
      X, 768, Wq, 768, bq, peQ, QG, 2304, 768, 18);

  // --- K path (gx=6, 768 blocks) ---
  pack_x<<<49152, 256, 0, stream>>>(k_r, k_i, X);
  PeTab peK{};
  peK.p[0] = pe_k_r; peK.sgn[0] = 1.f;
  peK.p[1] = pe_k_i; peK.sgn[1] = 1.f;
  gemm_kernel<MODE_PROJ><<<768, 256, 0, stream>>>(
      X, 768, Wk, 768, bk, peK, Kc, 768, 768, 6);

  // --- V path (transposed output Vt[bh][n][s]) ---
  pack_x<<<49152, 256, 0, stream>>>(v_r, v_i, X);
  gemm_kernel<MODE_VT><<<768, 256, 0, stream>>>(
      X, 768, Wv, 768, bv, pe0, Vt, 0, 768, 6);

  // --- attention ---
  score_kernel<<<2048, 256, 0, stream>>>(QG, Kc, P);
  softmax_kernel<<<32768, 64, 0, stream>>>(P);
  pv_kernel<<<768, 256, 0, stream>>>(P, Vt, A1, A2);

  // --- norm + diff + gate ---
  fuse_kernel<<<16384, 128, 0, stream>>>(A1, A2, QG, subln_w, lamp, Xatt);

  // --- output projection ---
  gemm_kernel<MODE_OUT><<<768, 256, 0, stream>>>(
      Xatt, 768, Wo, 768, bo, pe0, d_out, 0, 768, 6);

  (void)in_sizes; (void)n_in; (void)out_size;
}